// Round 1
// baseline (25.666 us; speedup 1.0000x reference)
//
#include <hip/hip_runtime.h>

#define BB 32
#define NN 256
#define DD 32
#define HH 64
#define TILE 32
#define PAD 68   // LDS row stride for A-tiles (floats): 16B-aligned rows, 2-way-max conflicts
#define WPAD 65  // LDS row stride for transposed W1

__device__ __forceinline__ float sigmoidf_fast(float v) {
    return 1.0f / (1.0f + __expf(-v));
}

// Core 32x32 edge-tile scoring from LDS-staged Ai/Ajb tiles.
// Thread layout: jl = tid&15 (fast dim -> coalesced stores), il = tid>>4.
// Each thread computes outputs (il,jl),(il,jl+16),(il+16,jl),(il+16,jl+16).
__device__ __forceinline__ void edge_tile_body(const float (*sAi)[PAD], const float (*sAj)[PAD],
                                               const float* sW2, float b2v, float* __restrict__ out,
                                               int b, int it, int jt)
{
    const int tid = threadIdx.x;
    const int jl = tid & 15;
    const int il = tid >> 4;
    float acc00 = 0.f, acc01 = 0.f, acc10 = 0.f, acc11 = 0.f;
#pragma unroll
    for (int h = 0; h < HH; h += 4) {
        float4 ai0 = *(const float4*)&sAi[il][h];        // broadcast within wave (4 distinct rows)
        float4 ai1 = *(const float4*)&sAi[il + 16][h];
        float4 aj0 = *(const float4*)&sAj[jl][h];        // 16 rows, stride 68 -> 2-way max (free)
        float4 aj1 = *(const float4*)&sAj[jl + 16][h];
        float4 w   = *(const float4*)&sW2[h];            // uniform broadcast

        acc00 += fmaxf(ai0.x + aj0.x, 0.f) * w.x;
        acc01 += fmaxf(ai0.x + aj1.x, 0.f) * w.x;
        acc10 += fmaxf(ai1.x + aj0.x, 0.f) * w.x;
        acc11 += fmaxf(ai1.x + aj1.x, 0.f) * w.x;

        acc00 += fmaxf(ai0.y + aj0.y, 0.f) * w.y;
        acc01 += fmaxf(ai0.y + aj1.y, 0.f) * w.y;
        acc10 += fmaxf(ai1.y + aj0.y, 0.f) * w.y;
        acc11 += fmaxf(ai1.y + aj1.y, 0.f) * w.y;

        acc00 += fmaxf(ai0.z + aj0.z, 0.f) * w.z;
        acc01 += fmaxf(ai0.z + aj1.z, 0.f) * w.z;
        acc10 += fmaxf(ai1.z + aj0.z, 0.f) * w.z;
        acc11 += fmaxf(ai1.z + aj1.z, 0.f) * w.z;

        acc00 += fmaxf(ai0.w + aj0.w, 0.f) * w.w;
        acc01 += fmaxf(ai0.w + aj1.w, 0.f) * w.w;
        acc10 += fmaxf(ai1.w + aj0.w, 0.f) * w.w;
        acc11 += fmaxf(ai1.w + aj1.w, 0.f) * w.w;
    }
    size_t base = ((size_t)b * NN + (size_t)it * TILE + il) * NN + (size_t)jt * TILE + jl;
    out[base]               = sigmoidf_fast(acc00 + b2v);
    out[base + 16]          = sigmoidf_fast(acc01 + b2v);
    out[base + 16 * NN]     = sigmoidf_fast(acc10 + b2v);
    out[base + 16 * NN + 16] = sigmoidf_fast(acc11 + b2v);
}

// Kernel 1: Ai[b,n,h] = sum_d x[b,n,d]*W1[h,d];  Ajb[b,n,h] = sum_d x[b,n,d]*W1[h,32+d] + b1[h]
// One block = 4 node rows, 64 threads (one per h) per row.
__global__ __launch_bounds__(256) void prep_kernel(const float* __restrict__ x, const float* __restrict__ W1,
                                                   const float* __restrict__ b1,
                                                   float* __restrict__ Ai, float* __restrict__ Ajb)
{
    __shared__ float sWt[64][WPAD];   // W1 transposed: sWt[d][h]
    __shared__ float sx[4][DD];
    const int tid = threadIdx.x;
    for (int k = tid; k < HH * 2 * DD; k += 256) {
        int h = k >> 6, dc = k & 63;
        sWt[dc][h] = W1[k];
    }
    const int rowBase = blockIdx.x * 4;
    if (tid < 4 * DD) sx[tid >> 5][tid & 31] = x[(size_t)rowBase * DD + tid];
    __syncthreads();
    const int r = tid >> 6;
    const int h = tid & 63;
    float a0 = 0.f;
    float a1 = b1[h];
#pragma unroll
    for (int d = 0; d < DD; ++d) {
        float xv = sx[r][d];
        a0 = fmaf(xv, sWt[d][h], a0);
        a1 = fmaf(xv, sWt[d + 32][h], a1);
    }
    size_t o = ((size_t)rowBase + r) * HH + h;
    Ai[o] = a0;
    Ajb[o] = a1;
}

// Kernel 2: stage tiles to LDS, score edges.
__global__ __launch_bounds__(256) void edge_kernel(const float* __restrict__ Ai, const float* __restrict__ Ajb,
                                                   const float* __restrict__ W2, const float* __restrict__ b2,
                                                   float* __restrict__ out)
{
    __shared__ float sAi[TILE][PAD];
    __shared__ float sAj[TILE][PAD];
    __shared__ float sW2[HH];
    const int blk = blockIdx.x;
    const int jt = blk & 7;
    const int it = (blk >> 3) & 7;
    const int b  = blk >> 6;
    const float* aiB = Ai  + ((size_t)b * NN + (size_t)it * TILE) * HH;
    const float* ajB = Ajb + ((size_t)b * NN + (size_t)jt * TILE) * HH;
    const int tid = threadIdx.x;
    // 32 rows x 64 floats = 512 float4 per tile; 256 threads -> 2 each
    for (int k = tid; k < TILE * HH / 4; k += 256) {
        int row = k >> 4, c4 = (k & 15) << 2;
        *(float4*)&sAi[row][c4] = *(const float4*)&aiB[row * HH + c4];
        *(float4*)&sAj[row][c4] = *(const float4*)&ajB[row * HH + c4];
    }
    if (tid < HH / 4) ((float4*)sW2)[tid] = ((const float4*)W2)[tid];
    __syncthreads();
    edge_tile_body(sAi, sAj, sW2, b2[0], out, b, it, jt);
}

// Fallback: fully fused (used only if d_ws is too small for Ai/Ajb).
__global__ __launch_bounds__(256) void fused_kernel(const float* __restrict__ x, const float* __restrict__ W1,
                                                    const float* __restrict__ b1, const float* __restrict__ W2,
                                                    const float* __restrict__ b2, float* __restrict__ out)
{
    __shared__ float sAi[TILE][PAD];
    __shared__ float sAj[TILE][PAD];
    __shared__ float sWt[64][WPAD];
    __shared__ float sxi[TILE][DD + 1];
    __shared__ float sxj[TILE][DD + 1];
    __shared__ float sW2[HH];
    __shared__ float sb1[HH];
    const int blk = blockIdx.x;
    const int jt = blk & 7;
    const int it = (blk >> 3) & 7;
    const int b  = blk >> 6;
    const int tid = threadIdx.x;
    for (int k = tid; k < HH * 2 * DD; k += 256) {
        int h = k >> 6, dc = k & 63;
        sWt[dc][h] = W1[k];
    }
    const float* xi = x + ((size_t)b * NN + (size_t)it * TILE) * DD;
    const float* xj = x + ((size_t)b * NN + (size_t)jt * TILE) * DD;
    for (int k = tid; k < TILE * DD; k += 256) {
        sxi[k >> 5][k & 31] = xi[k];
        sxj[k >> 5][k & 31] = xj[k];
    }
    if (tid < HH) { sW2[tid] = W2[tid]; sb1[tid] = b1[tid]; }
    __syncthreads();
    for (int k = tid; k < TILE * HH; k += 256) {
        int row = k >> 6, h = k & 63;
        float a0 = 0.f, a1 = sb1[h];
#pragma unroll
        for (int d = 0; d < DD; ++d) {
            a0 = fmaf(sxi[row][d], sWt[d][h], a0);
            a1 = fmaf(sxj[row][d], sWt[d + 32][h], a1);
        }
        sAi[row][h] = a0;
        sAj[row][h] = a1;
    }
    __syncthreads();
    edge_tile_body(sAi, sAj, sW2, b2[0], out, b, it, jt);
}

extern "C" void kernel_launch(void* const* d_in, const int* in_sizes, int n_in,
                              void* d_out, int out_size, void* d_ws, size_t ws_size,
                              hipStream_t stream) {
    const float* x  = (const float*)d_in[0];
    const float* W1 = (const float*)d_in[1];
    const float* b1 = (const float*)d_in[2];
    const float* W2 = (const float*)d_in[3];
    const float* b2 = (const float*)d_in[4];
    float* out = (float*)d_out;

    const size_t rows = (size_t)BB * NN;           // 8192
    const size_t need = rows * HH * 2 * sizeof(float);  // 4 MB
    const int nTiles = BB * (NN / TILE) * (NN / TILE);  // 2048

    if (ws_size >= need) {
        float* Ai  = (float*)d_ws;
        float* Ajb = Ai + rows * HH;
        prep_kernel<<<(int)(rows / 4), 256, 0, stream>>>(x, W1, b1, Ai, Ajb);
        edge_kernel<<<nTiles, 256, 0, stream>>>(Ai, Ajb, W2, b2, out);
    } else {
        fused_kernel<<<nTiles, 256, 0, stream>>>(x, W1, b1, W2, b2, out);
    }
}